// Round 1
// baseline (266.156 us; speedup 1.0000x reference)
//
#include <hip/hip_runtime.h>
#include <math.h>

// SSIM loss, fp32, N=16 C=3 H=W=512, 11x11 Gaussian (sigma=1.5), zero-padded
// depthwise conv. Separable blur: h-pass then v-pass over 5 channels
// (p, t, p^2, t^2, p*t). One block per 64x32 output tile.

#define IMG 512
#define NPLANES 48           // 16*3
#define TW 64
#define TH 32
#define HALO 5
#define IW (TW + 2*HALO)     // 74
#define IH (TH + 2*HALO)     // 42
#define C1 0.0001f           // 0.01^2
#define C2 0.0009f           // 0.03^2
#define NTOTAL 12582912.0f   // 16*3*512*512

struct GaussW { float g[11]; };

__global__ __launch_bounds__(256) void ssim_zero(float* accum) {
    accum[0] = 0.0f;
}

__global__ __launch_bounds__(256) void ssim_main(
    const float* __restrict__ pred,
    const float* __restrict__ target,
    float* __restrict__ accum,
    GaussW gw)
{
    __shared__ float sp[IH][IW];
    __shared__ float st[IH][IW];
    __shared__ float hb[5][IH][TW];
    __shared__ float red[4];

    const int tid = threadIdx.x;
    const int plane = blockIdx.z;
    const int tx0 = blockIdx.x * TW;
    const int ty0 = blockIdx.y * TH;
    const float* __restrict__ pbase = pred   + (size_t)plane * (IMG*IMG);
    const float* __restrict__ tbase = target + (size_t)plane * (IMG*IMG);

    // ---- Stage A: global -> LDS with halo, zero padding, (x+1)/2 fused ----
    float* spf = &sp[0][0];
    float* stf = &st[0][0];
    for (int i = tid; i < IH*IW; i += 256) {
        int r = i / IW, c = i - r*IW;
        int gy = ty0 + r - HALO;
        int gx = tx0 + c - HALO;
        float p = 0.0f, t = 0.0f;
        if (gy >= 0 && gy < IMG && gx >= 0 && gx < IMG) {
            p = (pbase[gy*IMG + gx] + 1.0f) * 0.5f;
            t = (tbase[gy*IMG + gx] + 1.0f) * 0.5f;
        }
        spf[i] = p;
        stf[i] = t;
    }
    __syncthreads();

    // ---- Stage B: horizontal blur, IH rows x TW cols, 5 channels ----
    for (int i = tid; i < IH*TW; i += 256) {
        int r = i / TW, c = i - r*TW;
        float ap = 0.f, at = 0.f, app = 0.f, att = 0.f, apt = 0.f;
        #pragma unroll
        for (int k = 0; k < 11; ++k) {
            float w = gw.g[k];
            float p = sp[r][c + k];
            float t = st[r][c + k];
            float wp = w * p;
            float wt = w * t;
            ap  += wp;
            at  += wt;
            app = fmaf(wp, p, app);
            att = fmaf(wt, t, att);
            apt = fmaf(wp, t, apt);
        }
        hb[0][r][c] = ap;
        hb[1][r][c] = at;
        hb[2][r][c] = app;
        hb[3][r][c] = att;
        hb[4][r][c] = apt;
    }
    __syncthreads();

    // ---- Stage C: vertical blur + SSIM + local sum ----
    float lsum = 0.0f;
    for (int i = tid; i < TH*TW; i += 256) {
        int r = i / TW, c = i - r*TW;
        float mp = 0.f, mt = 0.f, epp = 0.f, ett = 0.f, ept = 0.f;
        #pragma unroll
        for (int k = 0; k < 11; ++k) {
            float w = gw.g[k];
            mp  = fmaf(w, hb[0][r + k][c], mp);
            mt  = fmaf(w, hb[1][r + k][c], mt);
            epp = fmaf(w, hb[2][r + k][c], epp);
            ett = fmaf(w, hb[3][r + k][c], ett);
            ept = fmaf(w, hb[4][r + k][c], ept);
        }
        float mp2 = mp * mp;
        float mt2 = mt * mt;
        float mpt = mp * mt;
        float sig_p  = epp - mp2;
        float sig_t  = ett - mt2;
        float sig_pt = ept - mpt;
        float num = (2.0f * mpt + C1) * (2.0f * sig_pt + C2);
        float den = (mp2 + mt2 + C1) * (sig_p + sig_t + C2);
        lsum += num / den;
    }

    // ---- reduce: wave64 shuffle -> LDS -> one atomic per block ----
    #pragma unroll
    for (int off = 32; off > 0; off >>= 1)
        lsum += __shfl_down(lsum, off, 64);
    if ((tid & 63) == 0) red[tid >> 6] = lsum;
    __syncthreads();
    if (tid == 0) {
        float s = red[0] + red[1] + red[2] + red[3];
        atomicAdd(accum, s);
    }
}

__global__ __launch_bounds__(256) void ssim_final(const float* accum, float* out) {
    out[0] = 1.0f - accum[0] / NTOTAL;
}

extern "C" void kernel_launch(void* const* d_in, const int* in_sizes, int n_in,
                              void* d_out, int out_size, void* d_ws, size_t ws_size,
                              hipStream_t stream) {
    const float* pred   = (const float*)d_in[0];
    const float* target = (const float*)d_in[1];
    float* out   = (float*)d_out;
    float* accum = (float*)d_ws;

    // Gaussian window, computed in double then normalized (matches numpy ref)
    GaussW gw;
    double vals[11], s = 0.0;
    for (int i = 0; i < 11; ++i) {
        double d = (double)i - 5.0;
        vals[i] = exp(-(d * d) / (2.0 * 1.5 * 1.5));
        s += vals[i];
    }
    for (int i = 0; i < 11; ++i) gw.g[i] = (float)(vals[i] / s);

    ssim_zero<<<1, 1, 0, stream>>>(accum);
    dim3 grid(IMG / TW, IMG / TH, NPLANES);   // 8 x 16 x 48
    ssim_main<<<grid, 256, 0, stream>>>(pred, target, accum, gw);
    ssim_final<<<1, 1, 0, stream>>>(accum, out);
}

// Round 2
// 206.250 us; speedup vs baseline: 1.2905x; 1.2905x over previous
//
#include <hip/hip_runtime.h>
#include <hip/hip_fp16.h>
#include <math.h>

// SSIM loss, fp32 in/out, N=16 C=3 H=W=512, 11x11 Gaussian sigma=1.5,
// zero-padded depthwise conv, separable. Tile 64x16 per block, 256 threads.
// sp/st fp32 in LDS; h-blurred 5 channels stored fp16 (hb); stage C uses
// packed half2 FMA. LDS ~32.4 KB -> 4 blocks/CU with launch_bounds(256,4).

#define IMG   512
#define TW    64
#define TH    16
#define HALO  5
#define IW    76            // 74 used, padded to 76 (16B row alignment)
#define IH    (TH + 2*HALO) // 26
#define GX    (IMG / TW)    // 8
#define GY    (IMG / TH)    // 32
#define GZ    48            // 16*3
#define NB    (GX * GY * GZ) // 12288
#define C1c   0.0001f
#define C2c   0.0009f
#define NTOTAL 12582912.0f

struct GaussW { float g[11]; };

template <bool USE_ATOMIC>
__global__ __launch_bounds__(256, 4) void ssim_main(
    const float* __restrict__ pred,
    const float* __restrict__ target,
    float* __restrict__ sink,     // partials array (per-block) or single accum
    GaussW gw)
{
    __shared__ __align__(16) float sp[IH][IW];
    __shared__ __align__(16) float st[IH][IW];
    __shared__ __align__(16) __half hb[5][IH][TW];
    __shared__ float red[4];

    const int tid = threadIdx.x;
    const int tx0 = blockIdx.x * TW;
    const int ty0 = blockIdx.y * TH;
    const float* __restrict__ pbase = pred   + (size_t)blockIdx.z * (IMG*IMG);
    const float* __restrict__ tbase = target + (size_t)blockIdx.z * (IMG*IMG);

    // ---- Stage A: global -> LDS (fp32), halo, zero pad, (x+1)/2 fused ----
    for (int i = tid; i < IH * 74; i += 256) {
        int r = i / 74, c = i - r * 74;
        int gy = ty0 + r - HALO;
        int gx = tx0 + c - HALO;
        float p = 0.0f, t = 0.0f;
        if (gy >= 0 && gy < IMG && gx >= 0 && gx < IMG) {
            int idx = gy * IMG + gx;
            p = (pbase[idx] + 1.0f) * 0.5f;
            t = (tbase[idx] + 1.0f) * 0.5f;
        }
        sp[r][c] = p;
        st[r][c] = t;
    }
    __syncthreads();

    // ---- Stage B: horizontal blur, 4 outputs/thread, fp16 store ----
    // items: IH rows x 16 col-groups = 416
    for (int i = tid; i < IH * 16; i += 256) {
        int r = i >> 4, c4 = (i & 15) * 4;
        float pv[16], tv[16];
        const float4* sp4 = (const float4*)&sp[r][c4];
        const float4* st4 = (const float4*)&st[r][c4];
        #pragma unroll
        for (int q = 0; q < 4; ++q) {
            float4 a = sp4[q];
            pv[4*q+0] = a.x; pv[4*q+1] = a.y; pv[4*q+2] = a.z; pv[4*q+3] = a.w;
            float4 b = st4[q];
            tv[4*q+0] = b.x; tv[4*q+1] = b.y; tv[4*q+2] = b.z; tv[4*q+3] = b.w;
        }
        float ap[4] = {0,0,0,0}, at[4] = {0,0,0,0};
        float app[4] = {0,0,0,0}, att[4] = {0,0,0,0}, apt[4] = {0,0,0,0};
        #pragma unroll
        for (int k = 0; k < 11; ++k) {
            float w = gw.g[k];
            #pragma unroll
            for (int j = 0; j < 4; ++j) {
                float p = pv[k + j], t = tv[k + j];
                float wp = w * p, wt = w * t;
                ap[j] += wp;
                at[j] += wt;
                app[j] = fmaf(wp, p, app[j]);
                att[j] = fmaf(wt, t, att[j]);
                apt[j] = fmaf(wp, t, apt[j]);
            }
        }
        #pragma unroll
        for (int ch = 0; ch < 5; ++ch) {
            const float* src = (ch == 0) ? ap : (ch == 1) ? at : (ch == 2) ? app
                             : (ch == 3) ? att : apt;
            __half2 x01 = __floats2half2_rn(src[0], src[1]);
            __half2 x23 = __floats2half2_rn(src[2], src[3]);
            float2 packed;
            ((__half2*)&packed)[0] = x01;
            ((__half2*)&packed)[1] = x23;
            *(float2*)&hb[ch][r][c4] = packed;
        }
    }
    __syncthreads();

    // ---- Stage C: vertical blur (packed half2 FMA) + SSIM, 4 out/thread ----
    const int c4 = (tid & 15) * 4;
    const int r  = tid >> 4;
    __half2 acc[5][2];
    #pragma unroll
    for (int ch = 0; ch < 5; ++ch) {
        acc[ch][0] = __float2half2_rn(0.0f);
        acc[ch][1] = __float2half2_rn(0.0f);
    }
    #pragma unroll
    for (int k = 0; k < 11; ++k) {
        __half2 w2 = __float2half2_rn(gw.g[k]);
        #pragma unroll
        for (int ch = 0; ch < 5; ++ch) {
            float2 raw = *(const float2*)&hb[ch][r + k][c4];
            __half2 h01 = ((const __half2*)&raw)[0];
            __half2 h23 = ((const __half2*)&raw)[1];
            acc[ch][0] = __hfma2(w2, h01, acc[ch][0]);
            acc[ch][1] = __hfma2(w2, h23, acc[ch][1]);
        }
    }
    float vmp[4], vmt[4], vpp[4], vtt[4], vpt[4];
    #pragma unroll
    for (int h = 0; h < 2; ++h) {
        vmp[2*h] = __low2float(acc[0][h]); vmp[2*h+1] = __high2float(acc[0][h]);
        vmt[2*h] = __low2float(acc[1][h]); vmt[2*h+1] = __high2float(acc[1][h]);
        vpp[2*h] = __low2float(acc[2][h]); vpp[2*h+1] = __high2float(acc[2][h]);
        vtt[2*h] = __low2float(acc[3][h]); vtt[2*h+1] = __high2float(acc[3][h]);
        vpt[2*h] = __low2float(acc[4][h]); vpt[2*h+1] = __high2float(acc[4][h]);
    }
    float lsum = 0.0f;
    #pragma unroll
    for (int j = 0; j < 4; ++j) {
        float mp = vmp[j], mt = vmt[j];
        float mp2 = mp * mp, mt2 = mt * mt, mpt = mp * mt;
        float sig_p  = vpp[j] - mp2;
        float sig_t  = vtt[j] - mt2;
        float sig_pt = vpt[j] - mpt;
        float num = (2.0f * mpt + C1c) * (2.0f * sig_pt + C2c);
        float den = (mp2 + mt2 + C1c) * (sig_p + sig_t + C2c);
        lsum += num / den;
    }

    // ---- block reduction ----
    #pragma unroll
    for (int off = 32; off > 0; off >>= 1)
        lsum += __shfl_down(lsum, off, 64);
    if ((tid & 63) == 0) red[tid >> 6] = lsum;
    __syncthreads();
    if (tid == 0) {
        float s = red[0] + red[1] + red[2] + red[3];
        if (USE_ATOMIC) {
            atomicAdd(sink, s);
        } else {
            int bid = blockIdx.x + GX * (blockIdx.y + GY * blockIdx.z);
            sink[bid] = s;
        }
    }
}

__global__ __launch_bounds__(256) void ssim_reduce(const float* __restrict__ partials,
                                                   float* __restrict__ out)
{
    __shared__ float red[4];
    const int tid = threadIdx.x;
    float s = 0.0f;
    const float4* p4 = (const float4*)partials;
    #pragma unroll
    for (int j = 0; j < NB / 1024; ++j) {        // 12288/4 = 3072 float4 / 256
        float4 v = p4[tid + 256 * j];
        s += v.x + v.y + v.z + v.w;
    }
    #pragma unroll
    for (int off = 32; off > 0; off >>= 1)
        s += __shfl_down(s, off, 64);
    if ((tid & 63) == 0) red[tid >> 6] = s;
    __syncthreads();
    if (tid == 0)
        out[0] = 1.0f - (red[0] + red[1] + red[2] + red[3]) / NTOTAL;
}

__global__ void ssim_zero(float* accum) { accum[0] = 0.0f; }
__global__ void ssim_final(const float* accum, float* out) {
    out[0] = 1.0f - accum[0] / NTOTAL;
}

extern "C" void kernel_launch(void* const* d_in, const int* in_sizes, int n_in,
                              void* d_out, int out_size, void* d_ws, size_t ws_size,
                              hipStream_t stream) {
    const float* pred   = (const float*)d_in[0];
    const float* target = (const float*)d_in[1];
    float* out = (float*)d_out;

    GaussW gw;
    double vals[11], s = 0.0;
    for (int i = 0; i < 11; ++i) {
        double d = (double)i - 5.0;
        vals[i] = exp(-(d * d) / (2.0 * 1.5 * 1.5));
        s += vals[i];
    }
    for (int i = 0; i < 11; ++i) gw.g[i] = (float)(vals[i] / s);

    dim3 grid(GX, GY, GZ);   // 8 x 32 x 48 = 12288 blocks
    if (ws_size >= (size_t)NB * sizeof(float)) {
        float* partials = (float*)d_ws;
        ssim_main<false><<<grid, 256, 0, stream>>>(pred, target, partials, gw);
        ssim_reduce<<<1, 256, 0, stream>>>(partials, out);
    } else {
        float* accum = (float*)d_ws;
        ssim_zero<<<1, 1, 0, stream>>>(accum);
        ssim_main<true><<<grid, 256, 0, stream>>>(pred, target, accum, gw);
        ssim_final<<<1, 1, 0, stream>>>(accum, out);
    }
}

// Round 3
// 167.401 us; speedup vs baseline: 1.5899x; 1.2321x over previous
//
#include <hip/hip_runtime.h>
#include <math.h>

// SSIM loss, fp32, N=16 C=3 H=W=512, 11x11 Gaussian sigma=1.5, zero-padded
// depthwise conv, separable, VERTICAL PASS FIRST:
//   stage V: global -> registers (thread-per-column, coalesced), fuse
//            (x+1)/2 + products (p,t,p2,t2,pt), vertical 11-tap blur,
//            write v-blurred 5ch fp32 into LDS. No input staging, no
//            vertical halo recompute.
//   stage H: aligned float4 LDS reads, horizontal 11-tap blur, SSIM map,
//            block reduction -> per-block partial.
// LDS = 5*16*76*4 = 24.3 KB -> 6 blocks/CU (24 waves/CU).

#define IMG   512
#define TW    64
#define TH    16
#define HALO  5
#define IW    74             // v-blurred buffer columns (TW + 2*HALO)
#define IWP   76             // padded row stride in floats (16B-aligned rows)
#define NRG   4              // row groups (4 output rows each)
#define NSLOT (IW * NRG)     // 296 stage-V work items
#define GXD   8
#define GYD   32
#define GZD   48
#define NB    (GXD * GYD * GZD)   // 12288 blocks
#define C1c   0.0001f
#define C2c   0.0009f
#define NTOTAL 12582912.0f

struct GaussW { float g[11]; };

template <bool USE_ATOMIC>
__global__ __launch_bounds__(256, 6) void ssim_main(
    const float* __restrict__ pred,
    const float* __restrict__ target,
    float* __restrict__ sink,
    GaussW gw)
{
    __shared__ __align__(16) float hb[5][TH][IWP];  // 24320 B
    __shared__ float red[4];

    const int tid = threadIdx.x;
    const int tx0 = blockIdx.x * TW;
    const int ty0 = blockIdx.y * TH;
    const float* __restrict__ pbase = pred   + (size_t)blockIdx.z * (IMG*IMG);
    const float* __restrict__ tbase = target + (size_t)blockIdx.z * (IMG*IMG);

    // Block-uniform: true iff every load this block issues is in-bounds.
    const bool interior = (blockIdx.x >= 1) & (blockIdx.x <= GXD - 2) &
                          (blockIdx.y >= 1) & (blockIdx.y <= GYD - 2);

    // ---- Stage V: vertical blur of 5 channels, straight from global ----
    for (int slot = tid; slot < NSLOT; slot += 256) {
        const int rg = slot / IW;           // 0..3
        const int c  = slot - rg * IW;      // 0..73
        const int gx = tx0 - HALO + c;
        const int gy0 = ty0 + rg * 4 - HALO;   // first input row (14 rows)

        float pv[14], tv[14];
        if (interior) {
            const float* pp = pbase + (size_t)gy0 * IMG + gx;
            const float* tp = tbase + (size_t)gy0 * IMG + gx;
            #pragma unroll
            for (int k = 0; k < 14; ++k) {
                pv[k] = pp[k * IMG];
                tv[k] = tp[k * IMG];
            }
        } else {
            const bool xin = (gx >= 0) & (gx < IMG);
            #pragma unroll
            for (int k = 0; k < 14; ++k) {
                int gy = gy0 + k;
                bool in = xin & (gy >= 0) & (gy < IMG);
                int idx = in ? (gy * IMG + gx) : 0;
                float p = pbase[idx];
                float t = tbase[idx];
                pv[k] = in ? p : 0.0f;
                tv[k] = in ? t : 0.0f;
            }
        }

        float acc[5][4];
        #pragma unroll
        for (int ch = 0; ch < 5; ++ch)
            #pragma unroll
            for (int j = 0; j < 4; ++j) acc[ch][j] = 0.0f;

        #pragma unroll
        for (int k = 0; k < 14; ++k) {
            float ps = fmaf(pv[k], 0.5f, 0.5f);
            float ts = fmaf(tv[k], 0.5f, 0.5f);
            float v2 = ps * ps;
            float v3 = ts * ts;
            float v4 = ps * ts;
            #pragma unroll
            for (int j = 0; j < 4; ++j) {
                const int kk = k - j;
                if (kk >= 0 && kk < 11) {
                    float w = gw.g[kk];
                    acc[0][j] = fmaf(w, ps, acc[0][j]);
                    acc[1][j] = fmaf(w, ts, acc[1][j]);
                    acc[2][j] = fmaf(w, v2, acc[2][j]);
                    acc[3][j] = fmaf(w, v3, acc[3][j]);
                    acc[4][j] = fmaf(w, v4, acc[4][j]);
                }
            }
        }
        #pragma unroll
        for (int ch = 0; ch < 5; ++ch)
            #pragma unroll
            for (int j = 0; j < 4; ++j)
                hb[ch][rg * 4 + j][c] = acc[ch][j];
    }
    __syncthreads();

    // ---- Stage H: horizontal blur + SSIM, 4 outputs/thread ----
    const int r  = tid >> 4;          // 0..15
    const int c4 = (tid & 15) * 4;    // 0..60

    float res[5][4];
    #pragma unroll
    for (int ch = 0; ch < 5; ++ch) {
        const float* row = &hb[ch][r][c4];   // 16B-aligned (c4%4==0, IWP%4==0)
        float x[16];
        #pragma unroll
        for (int q = 0; q < 4; ++q) {
            float4 v = ((const float4*)row)[q];
            x[4*q+0] = v.x; x[4*q+1] = v.y; x[4*q+2] = v.z; x[4*q+3] = v.w;
        }
        float a0 = 0.f, a1 = 0.f, a2 = 0.f, a3 = 0.f;
        #pragma unroll
        for (int k = 0; k < 11; ++k) {
            float w = gw.g[k];
            a0 = fmaf(w, x[k + 0], a0);
            a1 = fmaf(w, x[k + 1], a1);
            a2 = fmaf(w, x[k + 2], a2);
            a3 = fmaf(w, x[k + 3], a3);
        }
        res[ch][0] = a0; res[ch][1] = a1; res[ch][2] = a2; res[ch][3] = a3;
    }

    float lsum = 0.0f;
    #pragma unroll
    for (int j = 0; j < 4; ++j) {
        float mp = res[0][j], mt = res[1][j];
        float mp2 = mp * mp, mt2 = mt * mt, mpt = mp * mt;
        float sig_p  = res[2][j] - mp2;
        float sig_t  = res[3][j] - mt2;
        float sig_pt = res[4][j] - mpt;
        float num = (2.0f * mpt + C1c) * (2.0f * sig_pt + C2c);
        float den = (mp2 + mt2 + C1c) * (sig_p + sig_t + C2c);
        lsum += num / den;
    }

    // ---- block reduction ----
    #pragma unroll
    for (int off = 32; off > 0; off >>= 1)
        lsum += __shfl_down(lsum, off, 64);
    if ((tid & 63) == 0) red[tid >> 6] = lsum;
    __syncthreads();
    if (tid == 0) {
        float s = red[0] + red[1] + red[2] + red[3];
        if (USE_ATOMIC) {
            atomicAdd(sink, s);
        } else {
            int bid = blockIdx.x + GXD * (blockIdx.y + GYD * blockIdx.z);
            sink[bid] = s;
        }
    }
}

__global__ __launch_bounds__(256) void ssim_reduce(const float* __restrict__ partials,
                                                   float* __restrict__ out)
{
    __shared__ float red[4];
    const int tid = threadIdx.x;
    float s = 0.0f;
    const float4* p4 = (const float4*)partials;
    #pragma unroll
    for (int j = 0; j < NB / 1024; ++j) {     // 12288/4 = 3072 float4 / 256
        float4 v = p4[tid + 256 * j];
        s += v.x + v.y + v.z + v.w;
    }
    #pragma unroll
    for (int off = 32; off > 0; off >>= 1)
        s += __shfl_down(s, off, 64);
    if ((tid & 63) == 0) red[tid >> 6] = s;
    __syncthreads();
    if (tid == 0)
        out[0] = 1.0f - (red[0] + red[1] + red[2] + red[3]) / NTOTAL;
}

__global__ void ssim_zero(float* accum) { accum[0] = 0.0f; }
__global__ void ssim_final(const float* accum, float* out) {
    out[0] = 1.0f - accum[0] / NTOTAL;
}

extern "C" void kernel_launch(void* const* d_in, const int* in_sizes, int n_in,
                              void* d_out, int out_size, void* d_ws, size_t ws_size,
                              hipStream_t stream) {
    const float* pred   = (const float*)d_in[0];
    const float* target = (const float*)d_in[1];
    float* out = (float*)d_out;

    GaussW gw;
    double vals[11], s = 0.0;
    for (int i = 0; i < 11; ++i) {
        double d = (double)i - 5.0;
        vals[i] = exp(-(d * d) / (2.0 * 1.5 * 1.5));
        s += vals[i];
    }
    for (int i = 0; i < 11; ++i) gw.g[i] = (float)(vals[i] / s);

    dim3 grid(GXD, GYD, GZD);   // 8 x 32 x 48
    if (ws_size >= (size_t)NB * sizeof(float)) {
        float* partials = (float*)d_ws;
        ssim_main<false><<<grid, 256, 0, stream>>>(pred, target, partials, gw);
        ssim_reduce<<<1, 256, 0, stream>>>(partials, out);
    } else {
        float* accum = (float*)d_ws;
        ssim_zero<<<1, 1, 0, stream>>>(accum);
        ssim_main<true><<<grid, 256, 0, stream>>>(pred, target, accum, gw);
        ssim_final<<<1, 1, 0, stream>>>(accum, out);
    }
}

// Round 4
// 141.433 us; speedup vs baseline: 1.8819x; 1.1836x over previous
//
#include <hip/hip_runtime.h>
#include <hip/hip_bf16.h>
#include <math.h>

// SSIM loss, fp32, N=16 C=3 H=W=512, 11x11 Gaussian sigma=1.5, zero-padded,
// separable — BOTH blur passes on the MFMA pipe (16x16x32 bf16):
//   W[i][k] = g[k-i] (16x32 band matrix, zeros elsewhere) serves both passes.
//   Pass V: D = mfma(Xfrag, Wfrag) -> V^T in C-layout -> lane holds 4
//           horizontally-contiguous v-blurred vals -> 1 ds_write_b64/channel.
//   Pass H: D = mfma(vb_frag, Wfrag) -> 4 SSIM pixels/lane, reg epilogue.
// Tile 16 rows x 64 cols per block (4 waves: wave w owns v-chunks {w, w+4<5}
// and output chunk w). LDS ~15.2 KB.

#define IMG 512
#define TW 64
#define TH 16
#define GXD 8
#define GYD 32
#define GZD 48
#define NB (GXD * GYD * GZD)   // 12288
#define VBS 88                 // vb row stride in bf16 (16B-aligned, conflict-free)
#define C1c 0.0001f
#define C2c 0.0009f
#define NTOTAL 12582912.0f

typedef short bf16x8 __attribute__((ext_vector_type(8)));
typedef float f32x4 __attribute__((ext_vector_type(4)));

struct GaussW { float g[11]; };

__device__ __forceinline__ unsigned int f2bf2(float a, float b) {
    union { __hip_bfloat162 h; unsigned int u; } cv;
    cv.h = __float22bfloat162_rn(make_float2(a, b));
    return cv.u;   // a in low 16 bits, b in high (little-endian struct {x,y})
}

template <bool USE_ATOMIC>
__global__ __launch_bounds__(256, 4) void ssim_main(
    const float* __restrict__ pred,
    const float* __restrict__ target,
    float* __restrict__ sink,
    GaussW gw)
{
    __shared__ unsigned short Wmat[16][32];       // 1 KB, band weights
    __shared__ unsigned short vb[5][16][VBS];     // 14080 B, v-blurred bf16
    __shared__ float red[4];

    const int tid  = threadIdx.x;
    const int w    = tid >> 6;        // wave 0..3
    const int lane = tid & 63;
    const int quad = lane >> 4;
    const int n16  = lane & 15;
    const int tx0  = blockIdx.x * TW;
    const int ty0  = blockIdx.y * TH;
    const float* __restrict__ pbase = pred   + (size_t)blockIdx.z * (IMG * IMG);
    const float* __restrict__ tbase = target + (size_t)blockIdx.z * (IMG * IMG);

    // ---- fill W: W[i][k] = g[k-i] for k-i in [0,10], else 0 ----
    for (int idx = tid; idx < 512; idx += 256) {
        int i = idx >> 5, k = idx & 31, d = k - i;
        float v = (d >= 0 && d <= 10) ? gw.g[d] : 0.0f;
        Wmat[i][k] = (unsigned short)(f2bf2(v, 0.0f) & 0xFFFFu);
    }
    __syncthreads();

    // one b128: lane's W fragment, reused as A-ish operand in both passes
    const bf16x8 wfrag = *(const bf16x8*)&Wmat[n16][quad * 8];

    const bool interior = (blockIdx.x >= 1) & (blockIdx.x <= GXD - 2) &
                          (blockIdx.y >= 1) & (blockIdx.y <= GYD - 2);
    const f32x4 z = {0.0f, 0.0f, 0.0f, 0.0f};

    // ---- Pass V: per owned v-chunk, global->frag->MFMA->LDS ----
    for (int vc = w; vc < 5; vc += 4) {
        const int gx = tx0 - 5 + 16 * vc + n16;   // input col for this lane
        const int k0 = quad * 8;                  // first input row (of 32)
        float pv[8], tv[8];
        if (interior) {
            const float* pp = pbase + (size_t)(ty0 - 5 + k0) * IMG + gx;
            const float* tp = tbase + (size_t)(ty0 - 5 + k0) * IMG + gx;
            #pragma unroll
            for (int j = 0; j < 8; ++j) {
                pv[j] = pp[j * IMG];
                tv[j] = tp[j * IMG];
            }
        } else {
            const bool xin = (unsigned)gx < (unsigned)IMG;
            #pragma unroll
            for (int j = 0; j < 8; ++j) {
                int gy = ty0 - 5 + k0 + j;
                bool in = xin && ((unsigned)gy < (unsigned)IMG);
                int idx = in ? (gy * IMG + gx) : 0;
                float a = pbase[idx];
                float b = tbase[idx];
                pv[j] = in ? a : 0.0f;
                tv[j] = in ? b : 0.0f;
            }
        }
        // products (fp32) -> bf16 fragments (B-layout: lane=col, 8q+j=row)
        union { bf16x8 v; unsigned int u[4]; } fP, fT, fPP, fTT, fPT;
        #pragma unroll
        for (int h = 0; h < 4; ++h) {
            float p0 = fmaf(pv[2*h],   0.5f, 0.5f);
            float p1 = fmaf(pv[2*h+1], 0.5f, 0.5f);
            float t0 = fmaf(tv[2*h],   0.5f, 0.5f);
            float t1 = fmaf(tv[2*h+1], 0.5f, 0.5f);
            fP.u[h]  = f2bf2(p0, p1);
            fT.u[h]  = f2bf2(t0, t1);
            fPP.u[h] = f2bf2(p0 * p0, p1 * p1);
            fTT.u[h] = f2bf2(t0 * t0, t1 * t1);
            fPT.u[h] = f2bf2(p0 * t0, p1 * t1);
        }
        // D = X^T . W^T  -> D[row'=vcol-in-chunk][col'=tile row] = V^T
        f32x4 d0 = __builtin_amdgcn_mfma_f32_16x16x32_bf16(fP.v,  wfrag, z, 0, 0, 0);
        f32x4 d1 = __builtin_amdgcn_mfma_f32_16x16x32_bf16(fT.v,  wfrag, z, 0, 0, 0);
        f32x4 d2 = __builtin_amdgcn_mfma_f32_16x16x32_bf16(fPP.v, wfrag, z, 0, 0, 0);
        f32x4 d3 = __builtin_amdgcn_mfma_f32_16x16x32_bf16(fTT.v, wfrag, z, 0, 0, 0);
        f32x4 d4 = __builtin_amdgcn_mfma_f32_16x16x32_bf16(fPT.v, wfrag, z, 0, 0, 0);
        // lane holds V[tile row n16][vcols 16vc+4q .. +3] -> one b64 per ch
        const int vcol = 16 * vc + 4 * quad;
        {
            union { ushort4 s; unsigned int u[2]; } pk;
            pk.u[0] = f2bf2(d0[0], d0[1]); pk.u[1] = f2bf2(d0[2], d0[3]);
            *(ushort4*)&vb[0][n16][vcol] = pk.s;
            pk.u[0] = f2bf2(d1[0], d1[1]); pk.u[1] = f2bf2(d1[2], d1[3]);
            *(ushort4*)&vb[1][n16][vcol] = pk.s;
            pk.u[0] = f2bf2(d2[0], d2[1]); pk.u[1] = f2bf2(d2[2], d2[3]);
            *(ushort4*)&vb[2][n16][vcol] = pk.s;
            pk.u[0] = f2bf2(d3[0], d3[1]); pk.u[1] = f2bf2(d3[2], d3[3]);
            *(ushort4*)&vb[3][n16][vcol] = pk.s;
            pk.u[0] = f2bf2(d4[0], d4[1]); pk.u[1] = f2bf2(d4[2], d4[3]);
            *(ushort4*)&vb[4][n16][vcol] = pk.s;
        }
    }
    __syncthreads();

    // ---- Pass H: wave w -> output cols 16w..16w+15 ----
    f32x4 r[5];
    #pragma unroll
    for (int ch = 0; ch < 5; ++ch) {
        bf16x8 a = *(const bf16x8*)&vb[ch][n16][16 * w + 8 * quad];
        r[ch] = __builtin_amdgcn_mfma_f32_16x16x32_bf16(a, wfrag, z, 0, 0, 0);
    }

    // ---- epilogue: 4 SSIM pixels per lane (rows 4q..4q+3, col 16w+n16) ----
    float lsum = 0.0f;
    #pragma unroll
    for (int j = 0; j < 4; ++j) {
        float mp = r[0][j], mt = r[1][j];
        float mp2 = mp * mp, mt2 = mt * mt, mpt = mp * mt;
        float sig_p  = r[2][j] - mp2;
        float sig_t  = r[3][j] - mt2;
        float sig_pt = r[4][j] - mpt;
        float num = (2.0f * mpt + C1c) * (2.0f * sig_pt + C2c);
        float den = (mp2 + mt2 + C1c) * (sig_p + sig_t + C2c);
        lsum += num / den;
    }

    // ---- block reduction ----
    #pragma unroll
    for (int off = 32; off > 0; off >>= 1)
        lsum += __shfl_down(lsum, off, 64);
    if (lane == 0) red[w] = lsum;
    __syncthreads();
    if (tid == 0) {
        float s = red[0] + red[1] + red[2] + red[3];
        if (USE_ATOMIC) {
            atomicAdd(sink, s);
        } else {
            int bid = blockIdx.x + GXD * (blockIdx.y + GYD * blockIdx.z);
            sink[bid] = s;
        }
    }
}

__global__ __launch_bounds__(256) void ssim_reduce(const float* __restrict__ partials,
                                                   float* __restrict__ out)
{
    __shared__ float red[4];
    const int tid = threadIdx.x;
    float s = 0.0f;
    const float4* p4 = (const float4*)partials;
    #pragma unroll
    for (int j = 0; j < NB / 1024; ++j) {   // 12288/4 = 3072 float4 / 256
        float4 v = p4[tid + 256 * j];
        s += v.x + v.y + v.z + v.w;
    }
    #pragma unroll
    for (int off = 32; off > 0; off >>= 1)
        s += __shfl_down(s, off, 64);
    if ((tid & 63) == 0) red[tid >> 6] = s;
    __syncthreads();
    if (tid == 0)
        out[0] = 1.0f - (red[0] + red[1] + red[2] + red[3]) / NTOTAL;
}

__global__ void ssim_zero(float* accum) { accum[0] = 0.0f; }
__global__ void ssim_final(const float* accum, float* out) {
    out[0] = 1.0f - accum[0] / NTOTAL;
}

extern "C" void kernel_launch(void* const* d_in, const int* in_sizes, int n_in,
                              void* d_out, int out_size, void* d_ws, size_t ws_size,
                              hipStream_t stream) {
    const float* pred   = (const float*)d_in[0];
    const float* target = (const float*)d_in[1];
    float* out = (float*)d_out;

    GaussW gw;
    double vals[11], s = 0.0;
    for (int i = 0; i < 11; ++i) {
        double d = (double)i - 5.0;
        vals[i] = exp(-(d * d) / (2.0 * 1.5 * 1.5));
        s += vals[i];
    }
    for (int i = 0; i < 11; ++i) gw.g[i] = (float)(vals[i] / s);

    dim3 grid(GXD, GYD, GZD);   // 8 x 32 x 48
    if (ws_size >= (size_t)NB * sizeof(float)) {
        float* partials = (float*)d_ws;
        ssim_main<false><<<grid, 256, 0, stream>>>(pred, target, partials, gw);
        ssim_reduce<<<1, 256, 0, stream>>>(partials, out);
    } else {
        float* accum = (float*)d_ws;
        ssim_zero<<<1, 1, 0, stream>>>(accum);
        ssim_main<true><<<grid, 256, 0, stream>>>(pred, target, accum, gw);
        ssim_final<<<1, 1, 0, stream>>>(accum, out);
    }
}

// Round 5
// 137.498 us; speedup vs baseline: 1.9357x; 1.0286x over previous
//
#include <hip/hip_runtime.h>
#include <math.h>

// SSIM loss, fp32, N=16 C=3 H=W=512, 11x11 Gaussian sigma=1.5, zero-padded,
// separable — both blur passes on the MFMA pipe (16x16x32 bf16).
//   W[i][k] = g[k-i] (16x32 band matrix) serves both passes; weights are
//   RNE-rounded to bf16 on the HOST. All device-side fp32->bf16 packing is
//   single-instruction v_perm_b32 truncation (bias cancels in SSIM ratio).
//   Epilogue uses v_rcp_f32 instead of exact divide.
// Tile 16 rows x 64 cols per block (4 waves). LDS ~15.2 KB.

#define IMG 512
#define TW 64
#define TH 16
#define GXD 8
#define GYD 32
#define GZD 48
#define NB (GXD * GYD * GZD)   // 12288
#define VBS 88                 // vb row stride in bf16 (16B-aligned)
#define C1c 0.0001f
#define C2c 0.0009f
#define NTOTAL 12582912.0f

typedef short bf16x8 __attribute__((ext_vector_type(8)));
typedef float f32x4 __attribute__((ext_vector_type(4)));

struct GaussB { unsigned short gb[11]; };   // bf16 weights (host-RNE)

// pack bf16(a) into low 16, bf16(b) into high 16 — one v_perm_b32 (truncate)
__device__ __forceinline__ unsigned int pkbf(float a, float b) {
    return __builtin_amdgcn_perm(__float_as_uint(b), __float_as_uint(a),
                                 0x07060302u);
}

template <bool USE_ATOMIC>
__global__ __launch_bounds__(256, 8) void ssim_main(
    const float* __restrict__ pred,
    const float* __restrict__ target,
    float* __restrict__ sink,
    GaussB gwb)
{
    __shared__ unsigned short Wmat[16][32];       // 1 KB
    __shared__ unsigned short vb[5][16][VBS];     // 14080 B
    __shared__ float red[4];

    const int tid  = threadIdx.x;
    const int w    = tid >> 6;        // wave 0..3
    const int lane = tid & 63;
    const int quad = lane >> 4;
    const int n16  = lane & 15;
    const int tx0  = blockIdx.x * TW;
    const int ty0  = blockIdx.y * TH;
    const float* __restrict__ pbase = pred   + (size_t)blockIdx.z * (IMG * IMG);
    const float* __restrict__ tbase = target + (size_t)blockIdx.z * (IMG * IMG);

    // ---- fill W: W[i][k] = g[k-i] for k-i in [0,10], else 0 ----
    for (int idx = tid; idx < 512; idx += 256) {
        int i = idx >> 5, k = idx & 31, d = k - i;
        Wmat[i][k] = (d >= 0 && d <= 10) ? gwb.gb[d] : 0;
    }
    __syncthreads();

    const bf16x8 wfrag = *(const bf16x8*)&Wmat[n16][quad * 8];

    const bool interior = (blockIdx.x >= 1) & (blockIdx.x <= GXD - 2) &
                          (blockIdx.y >= 1) & (blockIdx.y <= GYD - 2);
    const f32x4 z = {0.0f, 0.0f, 0.0f, 0.0f};

    // ---- Pass V: per owned v-chunk, global->frag->MFMA->LDS ----
    for (int vc = w; vc < 5; vc += 4) {
        const int gx = tx0 - 5 + 16 * vc + n16;
        const int k0 = quad * 8;
        float pv[8], tv[8];
        if (interior) {
            const float* pp = pbase + (size_t)(ty0 - 5 + k0) * IMG + gx;
            const float* tp = tbase + (size_t)(ty0 - 5 + k0) * IMG + gx;
            #pragma unroll
            for (int j = 0; j < 8; ++j) {
                pv[j] = pp[j * IMG];
                tv[j] = tp[j * IMG];
            }
        } else {
            const bool xin = (unsigned)gx < (unsigned)IMG;
            #pragma unroll
            for (int j = 0; j < 8; ++j) {
                int gy = ty0 - 5 + k0 + j;
                bool in = xin && ((unsigned)gy < (unsigned)IMG);
                int idx = in ? (gy * IMG + gx) : 0;
                float a = pbase[idx];
                float b = tbase[idx];
                pv[j] = in ? a : 0.0f;
                tv[j] = in ? b : 0.0f;
            }
        }
        union { bf16x8 v; unsigned int u[4]; } fP, fT, fPP, fTT, fPT;
        #pragma unroll
        for (int h = 0; h < 4; ++h) {
            float p0 = fmaf(pv[2*h],   0.5f, 0.5f);
            float p1 = fmaf(pv[2*h+1], 0.5f, 0.5f);
            float t0 = fmaf(tv[2*h],   0.5f, 0.5f);
            float t1 = fmaf(tv[2*h+1], 0.5f, 0.5f);
            fP.u[h]  = pkbf(p0, p1);
            fT.u[h]  = pkbf(t0, t1);
            fPP.u[h] = pkbf(p0 * p0, p1 * p1);
            fTT.u[h] = pkbf(t0 * t0, t1 * t1);
            fPT.u[h] = pkbf(p0 * t0, p1 * t1);
        }
        f32x4 d0 = __builtin_amdgcn_mfma_f32_16x16x32_bf16(fP.v,  wfrag, z, 0, 0, 0);
        f32x4 d1 = __builtin_amdgcn_mfma_f32_16x16x32_bf16(fT.v,  wfrag, z, 0, 0, 0);
        f32x4 d2 = __builtin_amdgcn_mfma_f32_16x16x32_bf16(fPP.v, wfrag, z, 0, 0, 0);
        f32x4 d3 = __builtin_amdgcn_mfma_f32_16x16x32_bf16(fTT.v, wfrag, z, 0, 0, 0);
        f32x4 d4 = __builtin_amdgcn_mfma_f32_16x16x32_bf16(fPT.v, wfrag, z, 0, 0, 0);
        const int vcol = 16 * vc + 4 * quad;
        {
            union { ushort4 s; unsigned int u[2]; } pk;
            pk.u[0] = pkbf(d0[0], d0[1]); pk.u[1] = pkbf(d0[2], d0[3]);
            *(ushort4*)&vb[0][n16][vcol] = pk.s;
            pk.u[0] = pkbf(d1[0], d1[1]); pk.u[1] = pkbf(d1[2], d1[3]);
            *(ushort4*)&vb[1][n16][vcol] = pk.s;
            pk.u[0] = pkbf(d2[0], d2[1]); pk.u[1] = pkbf(d2[2], d2[3]);
            *(ushort4*)&vb[2][n16][vcol] = pk.s;
            pk.u[0] = pkbf(d3[0], d3[1]); pk.u[1] = pkbf(d3[2], d3[3]);
            *(ushort4*)&vb[3][n16][vcol] = pk.s;
            pk.u[0] = pkbf(d4[0], d4[1]); pk.u[1] = pkbf(d4[2], d4[3]);
            *(ushort4*)&vb[4][n16][vcol] = pk.s;
        }
    }
    __syncthreads();

    // ---- Pass H: wave w -> output cols 16w..16w+15 ----
    f32x4 r[5];
    #pragma unroll
    for (int ch = 0; ch < 5; ++ch) {
        bf16x8 a = *(const bf16x8*)&vb[ch][n16][16 * w + 8 * quad];
        r[ch] = __builtin_amdgcn_mfma_f32_16x16x32_bf16(a, wfrag, z, 0, 0, 0);
    }

    // ---- epilogue: 4 SSIM pixels per lane ----
    float lsum = 0.0f;
    #pragma unroll
    for (int j = 0; j < 4; ++j) {
        float mp = r[0][j], mt = r[1][j];
        float mp2 = mp * mp, mt2 = mt * mt, mpt = mp * mt;
        float sig_p  = r[2][j] - mp2;
        float sig_t  = r[3][j] - mt2;
        float sig_pt = r[4][j] - mpt;
        float num = (2.0f * mpt + C1c) * (2.0f * sig_pt + C2c);
        float den = (mp2 + mt2 + C1c) * (sig_p + sig_t + C2c);
        lsum = fmaf(num, __builtin_amdgcn_rcpf(den), lsum);
    }

    // ---- block reduction ----
    #pragma unroll
    for (int off = 32; off > 0; off >>= 1)
        lsum += __shfl_down(lsum, off, 64);
    if (lane == 0) red[w] = lsum;
    __syncthreads();
    if (tid == 0) {
        float s = red[0] + red[1] + red[2] + red[3];
        if (USE_ATOMIC) {
            atomicAdd(sink, s);
        } else {
            int bid = blockIdx.x + GXD * (blockIdx.y + GYD * blockIdx.z);
            sink[bid] = s;
        }
    }
}

__global__ __launch_bounds__(256) void ssim_reduce(const float* __restrict__ partials,
                                                   float* __restrict__ out)
{
    __shared__ float red[4];
    const int tid = threadIdx.x;
    float s = 0.0f;
    const float4* p4 = (const float4*)partials;
    #pragma unroll
    for (int j = 0; j < NB / 1024; ++j) {
        float4 v = p4[tid + 256 * j];
        s += v.x + v.y + v.z + v.w;
    }
    #pragma unroll
    for (int off = 32; off > 0; off >>= 1)
        s += __shfl_down(s, off, 64);
    if ((tid & 63) == 0) red[tid >> 6] = s;
    __syncthreads();
    if (tid == 0)
        out[0] = 1.0f - (red[0] + red[1] + red[2] + red[3]) / NTOTAL;
}

__global__ void ssim_zero(float* accum) { accum[0] = 0.0f; }
__global__ void ssim_final(const float* accum, float* out) {
    out[0] = 1.0f - accum[0] / NTOTAL;
}

extern "C" void kernel_launch(void* const* d_in, const int* in_sizes, int n_in,
                              void* d_out, int out_size, void* d_ws, size_t ws_size,
                              hipStream_t stream) {
    const float* pred   = (const float*)d_in[0];
    const float* target = (const float*)d_in[1];
    float* out = (float*)d_out;

    // Gaussian weights in double, RNE-rounded to bf16 on host
    GaussB gwb;
    double vals[11], s = 0.0;
    for (int i = 0; i < 11; ++i) {
        double d = (double)i - 5.0;
        vals[i] = exp(-(d * d) / (2.0 * 1.5 * 1.5));
        s += vals[i];
    }
    for (int i = 0; i < 11; ++i) {
        float f = (float)(vals[i] / s);
        unsigned int u;
        __builtin_memcpy(&u, &f, 4);
        unsigned int rounded = (u + 0x7FFFu + ((u >> 16) & 1u)) >> 16;  // RNE
        gwb.gb[i] = (unsigned short)rounded;
    }

    dim3 grid(GXD, GYD, GZD);   // 8 x 32 x 48
    if (ws_size >= (size_t)NB * sizeof(float)) {
        float* partials = (float*)d_ws;
        ssim_main<false><<<grid, 256, 0, stream>>>(pred, target, partials, gwb);
        ssim_reduce<<<1, 256, 0, stream>>>(partials, out);
    } else {
        float* accum = (float*)d_ws;
        ssim_zero<<<1, 1, 0, stream>>>(accum);
        ssim_main<true><<<grid, 256, 0, stream>>>(pred, target, accum, gwb);
        ssim_final<<<1, 1, 0, stream>>>(accum, out);
    }
}